// Round 3
// baseline (632.151 us; speedup 1.0000x reference)
//
#include <hip/hip_runtime.h>

#define KSL 8
#define DIN 128
#define DOUT 128

typedef __attribute__((ext_vector_type(8))) short bf16x8;
typedef __attribute__((ext_vector_type(4))) float f32x4;

// round-to-nearest-even fp32 -> bf16 bits
static __device__ __forceinline__ unsigned int f2b_bits(float f) {
    unsigned int u = __float_as_uint(f);
    return (u + 0x7fffu + ((u >> 16) & 1u)) >> 16;
}

// ---------------- prep: x->bf16, deg count, W->bf16 [c][k] ----------------
__global__ __launch_bounds__(256) void prep(
        const float* __restrict__ x, uint4* __restrict__ xh, int n8,
        const int* __restrict__ dst, int E, int* __restrict__ deg,
        const float* __restrict__ W, unsigned short* __restrict__ Wh) {
    int tid = blockIdx.x * blockDim.x + threadIdx.x;
    int stride = gridDim.x * blockDim.x;

    for (int i = tid; i < n8; i += stride) {
        const float4* p = (const float4*)x + (size_t)i * 2;
        float4 a = p[0], b = p[1];
        uint4 o;
        o.x = f2b_bits(a.x) | (f2b_bits(a.y) << 16);
        o.y = f2b_bits(a.z) | (f2b_bits(a.w) << 16);
        o.z = f2b_bits(b.x) | (f2b_bits(b.y) << 16);
        o.w = f2b_bits(b.z) | (f2b_bits(b.w) << 16);
        xh[i] = o;
    }
    for (int e = tid; e < E; e += stride) atomicAdd(&deg[dst[e]], 1);

    // W^T as bf16: Wh[c*128 + k], 2048 uint4 chunks of 8 k's
    for (int i = tid; i < 2048; i += stride) {
        int c = i >> 4;
        int k0 = (i & 15) * 8;
        uint4 o;
        o.x = f2b_bits(W[(size_t)(k0 + 0) * 128 + c]) |
             (f2b_bits(W[(size_t)(k0 + 1) * 128 + c]) << 16);
        o.y = f2b_bits(W[(size_t)(k0 + 2) * 128 + c]) |
             (f2b_bits(W[(size_t)(k0 + 3) * 128 + c]) << 16);
        o.z = f2b_bits(W[(size_t)(k0 + 4) * 128 + c]) |
             (f2b_bits(W[(size_t)(k0 + 5) * 128 + c]) << 16);
        o.w = f2b_bits(W[(size_t)(k0 + 6) * 128 + c]) |
             (f2b_bits(W[(size_t)(k0 + 7) * 128 + c]) << 16);
        *(uint4*)(Wh + (size_t)c * 128 + k0) = o;
    }
}

// ---------------- CSR offsets: serial chunks + one block scan ----------------
__global__ __launch_bounds__(1024) void scan_off_fast(const int* __restrict__ deg, int N,
                                                      int* __restrict__ off,
                                                      float* __restrict__ dinv) {
    __shared__ int part[1024];
    int tid = threadIdx.x;
    int CH = (N + 1023) / 1024;
    int i0 = tid * CH;
    int s = 0;
    for (int j = 0; j < CH; j++) {
        int i = i0 + j;
        if (i < N) {
            int d = deg[i];
            dinv[i] = rsqrtf((float)(d + 1));   // +1 self-loop
            s += d;
        }
    }
    part[tid] = s;
    __syncthreads();
    for (int st = 1; st < 1024; st <<= 1) {
        int t = (tid >= st) ? part[tid - st] : 0;
        __syncthreads();
        part[tid] += t;
        __syncthreads();
    }
    int run = part[tid] - s;   // exclusive prefix
    for (int j = 0; j < CH; j++) {
        int i = i0 + j;
        if (i < N) {
            off[i] = run;
            run += deg[i];
        }
    }
    if (tid == 1023) off[N] = part[1023];
}

__global__ void fill_csr(const int* __restrict__ src, const int* __restrict__ dst, int E,
                         const int* __restrict__ off, int* __restrict__ cursor,
                         const float* __restrict__ dinv,
                         int2* __restrict__ csr) {
    int e = blockIdx.x * blockDim.x + threadIdx.x;
    if (e < E) {
        int s = src[e], d = dst[e];
        int pos = atomicAdd(&cursor[d], 1);
        csr[off[d] + pos] = make_int2(s, __float_as_int(dinv[s] * dinv[d]));
    }
}

// ---------------- fused aggregate + MFMA GEMM + bias + ReLU ----------------
// One wave per node-pair (16 rows of [N*K, 128]). Gather layout == MFMA A-frag
// layout: lane l owns row (l&15), elements d = kt*32 + (l>>4)*8 + e.
// No LDS: W read from global bf16 table (L2-hot). launch_bounds(256,8) -> VGPR<=64.
__global__ __launch_bounds__(256, 8) void aggemm(
        const char* __restrict__ xb,
        const int* __restrict__ off,
        const int2* __restrict__ csr,
        const float* __restrict__ dinv,
        const unsigned short* __restrict__ Wh, const float* __restrict__ bias,
        int N, float* __restrict__ out) {
    int t = threadIdx.x;
    int wid = t >> 6, lane = t & 63;
    int pair = blockIdx.x * 4 + wid;
    int n0 = pair * 2;
    if (n0 >= N) return;

    int rit = lane & 15;          // row in 16-row tile
    int g   = lane >> 4;          // k-group 0..3
    int mynode = n0 + (rit >> 3);
    if (mynode >= N) mynode = n0; // odd-N guard
    int kslice = rit & 7;

    int offA = off[n0];
    int offMid = off[n0 + 1];
    int offEnd = (n0 + 2 <= N) ? off[n0 + 2] : offMid;
    int degA = offMid - offA;
    int degB = (n0 + 1 < N) ? (offEnd - offMid) : 0;
    int maxd = max(degA, degB);
    int myoff = (rit < 8) ? offA : offMid;
    int mydeg = (rit < 8) ? degA : degB;

    float acc[32];
    #pragma unroll
    for (int i = 0; i < 32; i++) acc[i] = 0.f;

    float dself = dinv[mynode];
    for (int j = -1; j < maxd; j++) {
        int s;
        float nrm;
        if (j < 0) {
            s = mynode;
            nrm = dself * dself;
        } else if (j < mydeg) {
            int2 cc = csr[myoff + j];
            s = cc.x;
            nrm = __int_as_float(cc.y);
        } else {
            s = mynode;
            nrm = 0.f;
        }
        const char* rb = xb + (size_t)s * 2048 + kslice * 256 + g * 16;
        #pragma unroll
        for (int kt = 0; kt < 4; kt++) {
            uint4 q = *(const uint4*)(rb + kt * 64);
            acc[kt * 8 + 0] += __uint_as_float(q.x << 16) * nrm;
            acc[kt * 8 + 1] += __uint_as_float(q.x & 0xffff0000u) * nrm;
            acc[kt * 8 + 2] += __uint_as_float(q.y << 16) * nrm;
            acc[kt * 8 + 3] += __uint_as_float(q.y & 0xffff0000u) * nrm;
            acc[kt * 8 + 4] += __uint_as_float(q.z << 16) * nrm;
            acc[kt * 8 + 5] += __uint_as_float(q.z & 0xffff0000u) * nrm;
            acc[kt * 8 + 6] += __uint_as_float(q.w << 16) * nrm;
            acc[kt * 8 + 7] += __uint_as_float(q.w & 0xffff0000u) * nrm;
        }
    }

    // pack accumulators -> A fragments (bf16)
    bf16x8 afrag[4];
    #pragma unroll
    for (int kt = 0; kt < 4; kt++) {
        #pragma unroll
        for (int e = 0; e < 8; e++)
            afrag[kt][e] = (short)f2b_bits(acc[kt * 8 + e]);
    }

    // GEMM: 8 column tiles of 16, K = 128 in 4 MFMAs each; B-frags from global
    long long r0 = (long long)n0 * 8;
    #pragma unroll
    for (int ct = 0; ct < 8; ct++) {
        int c = ct * 16 + rit;     // output column (C/D: col = lane&15)
        f32x4 acct = {0.f, 0.f, 0.f, 0.f};
        #pragma unroll
        for (int kt = 0; kt < 4; kt++) {
            bf16x8 bfrag = *(const bf16x8*)(Wh + (size_t)c * 128 + kt * 32 + g * 8);
            acct = __builtin_amdgcn_mfma_f32_16x16x32_bf16(afrag[kt], bfrag, acct, 0, 0, 0);
        }
        float bv = bias[c];
        #pragma unroll
        for (int r = 0; r < 4; r++) {
            long long row = r0 + g * 4 + r;   // C/D: row = (lane>>4)*4 + reg
            __builtin_nontemporal_store(fmaxf(acct[r] + bv, 0.f),
                                        &out[row * 128 + c]);
        }
    }
}

// ---------------- launch ----------------
extern "C" void kernel_launch(void* const* d_in, const int* in_sizes, int n_in,
                              void* d_out, int out_size, void* d_ws, size_t ws_size,
                              hipStream_t stream) {
    const float* x  = (const float*)d_in[0];
    const int*   ei = (const int*)d_in[1];
    const float* W  = (const float*)d_in[2];
    const float* b  = (const float*)d_in[3];
    float* out = (float*)d_out;

    int N = in_sizes[0] / (KSL * DIN);
    int E = in_sizes[1] / 2;
    const int* src = ei;
    const int* dst = ei + E;

    char* ws = (char*)d_ws;
    size_t o = 0;
    auto alloc = [&](size_t bytes) -> void* {
        o = (o + 255) & ~(size_t)255;
        void* p = ws + o;
        o += bytes;
        return p;
    };
    int*   deg    = (int*)alloc((size_t)N * 4);
    int*   off    = (int*)alloc((size_t)(N + 1) * 4);
    int*   cursor = (int*)alloc((size_t)N * 4);
    float* dinv   = (float*)alloc((size_t)N * 4);
    int2*  csr    = (int2*)alloc((size_t)(E + 1) * 8);
    unsigned short* Wh = (unsigned short*)alloc((size_t)DIN * DOUT * 2);
    uint4* xh     = (uint4*)alloc((size_t)N * KSL * DIN * 2);

    hipMemsetAsync(deg, 0, (size_t)N * 4, stream);
    hipMemsetAsync(cursor, 0, (size_t)N * 4, stream);

    int n8 = N * KSL * DIN / 8;
    prep<<<2048, 256, 0, stream>>>(x, xh, n8, dst, E, deg, W, Wh);
    scan_off_fast<<<1, 1024, 0, stream>>>(deg, N, off, dinv);
    fill_csr<<<(E + 255) / 256, 256, 0, stream>>>(src, dst, E, off, cursor, dinv, csr);

    int pairs = (N + 1) / 2;
    int blocks = (pairs + 3) / 4;
    aggemm<<<blocks, 256, 0, stream>>>((const char*)xh, off, csr, dinv,
                                       Wh, b, N, out);
}

// Round 5
// 630.425 us; speedup vs baseline: 1.0027x; 1.0027x over previous
//
#include <hip/hip_runtime.h>

#define KSL 8
#define DIN 128
#define DOUT 128

typedef __attribute__((ext_vector_type(8))) short bf16x8;
typedef __attribute__((ext_vector_type(4))) float f32x4;

// round-to-nearest-even fp32 -> bf16 bits
static __device__ __forceinline__ unsigned int f2b_bits(float f) {
    unsigned int u = __float_as_uint(f);
    return (u + 0x7fffu + ((u >> 16) & 1u)) >> 16;
}

// ---------------- prep: x->bf16, deg count, W->bf16 [c][k] ----------------
__global__ __launch_bounds__(256) void prep(
        const float* __restrict__ x, uint4* __restrict__ xh, int n8,
        const int* __restrict__ dst, int E, int* __restrict__ deg,
        const float* __restrict__ W, unsigned short* __restrict__ Wh) {
    int tid = blockIdx.x * blockDim.x + threadIdx.x;
    int stride = gridDim.x * blockDim.x;

    for (int i = tid; i < n8; i += stride) {
        const float4* p = (const float4*)x + (size_t)i * 2;
        float4 a = p[0], b = p[1];
        uint4 o;
        o.x = f2b_bits(a.x) | (f2b_bits(a.y) << 16);
        o.y = f2b_bits(a.z) | (f2b_bits(a.w) << 16);
        o.z = f2b_bits(b.x) | (f2b_bits(b.y) << 16);
        o.w = f2b_bits(b.z) | (f2b_bits(b.w) << 16);
        xh[i] = o;
    }
    for (int e = tid; e < E; e += stride) atomicAdd(&deg[dst[e]], 1);

    // W^T as bf16: Wh[c*128 + k], 2048 uint4 chunks of 8 k's
    for (int i = tid; i < 2048; i += stride) {
        int c = i >> 4;
        int k0 = (i & 15) * 8;
        uint4 o;
        o.x = f2b_bits(W[(size_t)(k0 + 0) * 128 + c]) |
             (f2b_bits(W[(size_t)(k0 + 1) * 128 + c]) << 16);
        o.y = f2b_bits(W[(size_t)(k0 + 2) * 128 + c]) |
             (f2b_bits(W[(size_t)(k0 + 3) * 128 + c]) << 16);
        o.z = f2b_bits(W[(size_t)(k0 + 4) * 128 + c]) |
             (f2b_bits(W[(size_t)(k0 + 5) * 128 + c]) << 16);
        o.w = f2b_bits(W[(size_t)(k0 + 6) * 128 + c]) |
             (f2b_bits(W[(size_t)(k0 + 7) * 128 + c]) << 16);
        *(uint4*)(Wh + (size_t)c * 128 + k0) = o;
    }
}

// ---------------- CSR offsets: serial chunks + one block scan ----------------
__global__ __launch_bounds__(1024) void scan_off_fast(const int* __restrict__ deg, int N,
                                                      int* __restrict__ off,
                                                      float* __restrict__ dinv) {
    __shared__ int part[1024];
    int tid = threadIdx.x;
    int CH = (N + 1023) / 1024;
    int i0 = tid * CH;
    int s = 0;
    for (int j = 0; j < CH; j++) {
        int i = i0 + j;
        if (i < N) {
            int d = deg[i];
            dinv[i] = rsqrtf((float)(d + 1));   // +1 self-loop
            s += d;
        }
    }
    part[tid] = s;
    __syncthreads();
    for (int st = 1; st < 1024; st <<= 1) {
        int t = (tid >= st) ? part[tid - st] : 0;
        __syncthreads();
        part[tid] += t;
        __syncthreads();
    }
    int run = part[tid] - s;   // exclusive prefix
    for (int j = 0; j < CH; j++) {
        int i = i0 + j;
        if (i < N) {
            off[i] = run;
            run += deg[i];
        }
    }
    if (tid == 1023) off[N] = part[1023];
}

__global__ void fill_csr(const int* __restrict__ src, const int* __restrict__ dst, int E,
                         const int* __restrict__ off, int* __restrict__ cursor,
                         const float* __restrict__ dinv,
                         int2* __restrict__ csr) {
    int e = blockIdx.x * blockDim.x + threadIdx.x;
    if (e < E) {
        int s = src[e], d = dst[e];
        int pos = atomicAdd(&cursor[d], 1);
        csr[off[d] + pos] = make_int2(s, __float_as_int(dinv[s] * dinv[d]));
    }
}

// ---------------- fused aggregate + MFMA GEMM + bias + ReLU ----------------
// One wave per node-pair (16 rows of [N*K, 128]). Gather layout == MFMA
// fragment layout: lane l owns row (l&15), elements d = kt*32 + (l>>4)*8 + e.
// SWAPPED-OPERAND epilogue: acct = mfma(W_frag, X_frag) so D is transposed:
// lane l holds out[n0*8 + (l&15)][ct*16 + (l>>4)*4 .. +3] -> float4 stores.
// No LDS (proven deterministic base, round 3). launch_bounds(256,8) -> VGPR<=64.
__global__ __launch_bounds__(256, 8) void aggemm(
        const char* __restrict__ xb,
        const int* __restrict__ off,
        const int2* __restrict__ csr,
        const float* __restrict__ dinv,
        const unsigned short* __restrict__ Wh, const float* __restrict__ bias,
        int N, float* __restrict__ out) {
    int t = threadIdx.x;
    int wid = t >> 6, lane = t & 63;
    int pair = blockIdx.x * 4 + wid;
    int n0 = pair * 2;
    if (n0 >= N) return;

    int rit = lane & 15;          // row in 16-row tile (also output row, also W col within tile)
    int g   = lane >> 4;          // k-group 0..3
    int mynode = n0 + (rit >> 3);
    bool rowok = (mynode < N);    // odd-N guard
    if (!rowok) mynode = n0;
    int kslice = rit & 7;

    int offA = off[n0];
    int offMid = off[n0 + 1];
    int offEnd = (n0 + 2 <= N) ? off[n0 + 2] : offMid;
    int degA = offMid - offA;
    int degB = (n0 + 1 < N) ? (offEnd - offMid) : 0;
    int maxd = max(degA, degB);
    int myoff = (rit < 8) ? offA : offMid;
    int mydeg = (rit < 8) ? degA : degB;

    float acc[32];
    #pragma unroll
    for (int i = 0; i < 32; i++) acc[i] = 0.f;

    float dself = dinv[mynode];
    for (int j = -1; j < maxd; j++) {
        int s;
        float nrm;
        if (j < 0) {
            s = mynode;
            nrm = dself * dself;
        } else if (j < mydeg) {
            int2 cc = csr[myoff + j];
            s = cc.x;
            nrm = __int_as_float(cc.y);
        } else {
            s = mynode;
            nrm = 0.f;
        }
        const char* rb = xb + (size_t)s * 2048 + kslice * 256 + g * 16;
        #pragma unroll
        for (int kt = 0; kt < 4; kt++) {
            uint4 q = *(const uint4*)(rb + kt * 64);
            acc[kt * 8 + 0] += __uint_as_float(q.x << 16) * nrm;
            acc[kt * 8 + 1] += __uint_as_float(q.x & 0xffff0000u) * nrm;
            acc[kt * 8 + 2] += __uint_as_float(q.y << 16) * nrm;
            acc[kt * 8 + 3] += __uint_as_float(q.y & 0xffff0000u) * nrm;
            acc[kt * 8 + 4] += __uint_as_float(q.z << 16) * nrm;
            acc[kt * 8 + 5] += __uint_as_float(q.z & 0xffff0000u) * nrm;
            acc[kt * 8 + 6] += __uint_as_float(q.w << 16) * nrm;
            acc[kt * 8 + 7] += __uint_as_float(q.w & 0xffff0000u) * nrm;
        }
    }

    // pack accumulators -> bf16 fragments (valid as either A- or B-operand:
    // A: row=l&15, k=(l>>4)*8+e  /  B: col=l&15, k=(l>>4)*8+e — same registers)
    bf16x8 xfrag[4];
    #pragma unroll
    for (int kt = 0; kt < 4; kt++) {
        #pragma unroll
        for (int e = 0; e < 8; e++)
            xfrag[kt][e] = (short)f2b_bits(acc[kt * 8 + e]);
    }

    // Swapped GEMM: D = (W^T_tile) x (Xagg^T)  =>  D[m][n] = out[row n][col ct*16+m].
    // Lane l: n = l&15 = rit (its output row), m = g*4 + reg -> 4 consecutive cols.
    long long row = (long long)n0 * 8 + rit;
    #pragma unroll
    for (int ct = 0; ct < 8; ct++) {
        int c0 = ct * 16;
        f32x4 acct = {0.f, 0.f, 0.f, 0.f};
        #pragma unroll
        for (int kt = 0; kt < 4; kt++) {
            // A-frag: lane l holds W[k][c0 + (l&15)] = Wh[(c0+rit)*128 + k]
            bf16x8 wfrag = *(const bf16x8*)(Wh + (size_t)(c0 + rit) * 128 + kt * 32 + g * 8);
            acct = __builtin_amdgcn_mfma_f32_16x16x32_bf16(wfrag, xfrag[kt], acct, 0, 0, 0);
        }
        if (rowok) {
            float4 bv = *(const float4*)(bias + c0 + g * 4);
            float4 o;
            o.x = fmaxf(acct[0] + bv.x, 0.f);
            o.y = fmaxf(acct[1] + bv.y, 0.f);
            o.z = fmaxf(acct[2] + bv.z, 0.f);
            o.w = fmaxf(acct[3] + bv.w, 0.f);
            *(float4*)(out + row * 128 + c0 + g * 4) = o;
        }
    }
}

// ---------------- launch ----------------
extern "C" void kernel_launch(void* const* d_in, const int* in_sizes, int n_in,
                              void* d_out, int out_size, void* d_ws, size_t ws_size,
                              hipStream_t stream) {
    const float* x  = (const float*)d_in[0];
    const int*   ei = (const int*)d_in[1];
    const float* W  = (const float*)d_in[2];
    const float* b  = (const float*)d_in[3];
    float* out = (float*)d_out;

    int N = in_sizes[0] / (KSL * DIN);
    int E = in_sizes[1] / 2;
    const int* src = ei;
    const int* dst = ei + E;

    char* ws = (char*)d_ws;
    size_t o = 0;
    auto alloc = [&](size_t bytes) -> void* {
        o = (o + 255) & ~(size_t)255;
        void* p = ws + o;
        o += bytes;
        return p;
    };
    int*   deg    = (int*)alloc((size_t)N * 4);
    int*   off    = (int*)alloc((size_t)(N + 1) * 4);
    int*   cursor = (int*)alloc((size_t)N * 4);
    float* dinv   = (float*)alloc((size_t)N * 4);
    int2*  csr    = (int2*)alloc((size_t)(E + 1) * 8);
    unsigned short* Wh = (unsigned short*)alloc((size_t)DIN * DOUT * 2);
    uint4* xh     = (uint4*)alloc((size_t)N * KSL * DIN * 2);

    hipMemsetAsync(deg, 0, (size_t)N * 4, stream);
    hipMemsetAsync(cursor, 0, (size_t)N * 4, stream);

    int n8 = N * KSL * DIN / 8;
    prep<<<2048, 256, 0, stream>>>(x, xh, n8, dst, E, deg, W, Wh);
    scan_off_fast<<<1, 1024, 0, stream>>>(deg, N, off, dinv);
    fill_csr<<<(E + 255) / 256, 256, 0, stream>>>(src, dst, E, off, cursor, dinv, csr);

    int pairs = (N + 1) / 2;
    int blocks = (pairs + 3) / 4;
    aggemm<<<blocks, 256, 0, stream>>>((const char*)xh, off, csr, dinv,
                                       Wh, b, N, out);
}